// Round 5
// baseline (462.959 us; speedup 1.0000x reference)
//
#include <hip/hip_runtime.h>

// Problem constants (from reference): B=64, T=2048, D=64, V=100000
#define BB 64
#define TT 2048
#define DD 64
#define BT (BB * TT)                 // 131072
#define OFF_F 0                      // features [B,T,256]
#define OFF_T (BT * 256)             // times    [B,T]        = 33554432
#define OFF_D (OFF_T + BT)           // delta    [B,T,256]    = 33685504
#define OFF_M (OFF_D + BT * 256)     // mask     [B,T,256]    = 67239936

// ---------------------------------------------------------------------------
// Phase 1: beta linear recurrence. One block = one wave per (f,b) sequence,
// 256 blocks -> 1 block/CU. Fully register-resident: each lane float4-loads
// its 32-step window (t, v) straight from global; no LDS, no barrier.
// beta[i] = a_i*beta[i-1] + c_i, a_i = m_{i-1}*pad_i (0/1), c_i = dt_i*pad_i.
// Exact arithmetic (0/1 multipliers, integer-valued times) -> bitwise equal
// to the reference serial scan.
// f==0 blocks also emit the `times` output copy from registers (free).
// Output layout: beta_ws[(b*TT+i)*4 + f]  (token-major float4 per token).
// ---------------------------------------------------------------------------
__global__ __launch_bounds__(64) void beta_scan_kernel(
    const int* __restrict__ cat1, const int* __restrict__ cat2,
    const float* __restrict__ num1, const float* __restrict__ num2,
    const float* __restrict__ times, float* __restrict__ beta_ws,
    float* __restrict__ out)
{
    const int f    = blockIdx.x >> 6;
    const int b    = blockIdx.x & 63;
    const int lane = threadIdx.x;
    const int lo   = lane * 32;

    const float* trow = times + b * TT;

    float t[32], v[32];
    {
        const float4* t4 = (const float4*)(trow + lo);
        #pragma unroll
        for (int q = 0; q < 8; ++q) {
            float4 x = t4[q];
            t[4*q+0] = x.x; t[4*q+1] = x.y; t[4*q+2] = x.z; t[4*q+3] = x.w;
        }
    }
    // wave-uniform branch: f constant per block
    if (f < 2) {
        const int* crow = (f == 0 ? cat1 : cat2) + b * TT;
        const int4* c4 = (const int4*)(crow + lo);
        #pragma unroll
        for (int q = 0; q < 8; ++q) {
            int4 x = c4[q];
            v[4*q+0] = (float)x.x; v[4*q+1] = (float)x.y;
            v[4*q+2] = (float)x.z; v[4*q+3] = (float)x.w;
        }
    } else {
        const float* nrow = (f == 2 ? num1 : num2) + b * TT;
        const float4* n4 = (const float4*)(nrow + lo);
        #pragma unroll
        for (int q = 0; q < 8; ++q) {
            float4 x = n4[q];
            v[4*q+0] = x.x; v[4*q+1] = x.y; v[4*q+2] = x.z; v[4*q+3] = x.w;
        }
    }
    // times output copy from registers (f==0 blocks only; wave-uniform)
    if (f == 0) {
        float4* tdst = (float4*)(out + OFF_T + b * TT + lo);
        #pragma unroll
        for (int q = 0; q < 8; ++q) {
            tdst[q] = make_float4(t[4*q+0], t[4*q+1], t[4*q+2], t[4*q+3]);
        }
    }
    // boundary values for k==0 (lane>0 reads element lo-1)
    float tprev = 0.f, vprev = 0.f;
    if (lane > 0) {
        tprev = trow[lo - 1];
        if      (f == 0) vprev = (float)cat1[b * TT + lo - 1];
        else if (f == 1) vprev = (float)cat2[b * TT + lo - 1];
        else if (f == 2) vprev = num1[b * TT + lo - 1];
        else             vprev = num2[b * TT + lo - 1];
    }

    // pass 1: compose this lane's 32 affine steps
    float A = 1.f, C = 0.f;
    #pragma unroll
    for (int k = 0; k < 32; ++k) {
        float a, c;
        if (lo + k == 0) { a = 0.f; c = 0.f; }          // beta[0] = 0
        else {
            float ti  = t[k];
            float tp  = (k == 0) ? tprev : t[k-1];
            float fv  = (k == 0) ? vprev : v[k-1];
            float pad = (ti != -1.f) ? 1.f : 0.f;
            float m   = (fv != -1.f && fv != 0.f) ? 1.f : 0.f;
            a = m * pad;
            c = (ti - tp) * pad;
        }
        C = a * C + c;
        A = A * a;
    }
    // inclusive wave scan (affine composition)
    for (int d = 1; d < 64; d <<= 1) {
        float Ap = __shfl_up(A, d);
        float Cp = __shfl_up(C, d);
        if (lane >= d) { C = A * Cp + C; A = A * Ap; }
    }
    float beta = __shfl_up(C, 1);
    if (lane == 0) beta = 0.f;

    // pass 2: replay with true incoming beta, write token-major [bt][f]
    float* bout = beta_ws + (size_t)b * TT * 4 + f;
    #pragma unroll
    for (int k = 0; k < 32; ++k) {
        float a, c;
        if (lo + k == 0) { a = 0.f; c = 0.f; }
        else {
            float ti  = t[k];
            float tp  = (k == 0) ? tprev : t[k-1];
            float fv  = (k == 0) ? vprev : v[k-1];
            float pad = (ti != -1.f) ? 1.f : 0.f;
            float m   = (fv != -1.f && fv != 0.f) ? 1.f : 0.f;
            a = m * pad;
            c = (ti - tp) * pad;
        }
        beta = a * beta + c;
        bout[(lo + k) * 4] = beta;
    }
}

// ---------------------------------------------------------------------------
// Phase 2: expansion. One thread per (token bt, float4-chunk c in [0,16)),
// all 4 features per thread -> branch-free, 2M threads.
// __launch_bounds__(256,8): cap VGPRs so 8 waves/SIMD hide the dependent
// cat[bt] -> E[idx] gather latency. A/B this round: REGULAR stores
// (L2-buffered) instead of nontemporal — the harness fill sustains
// 6.3 TB/s through L2, testing whether nt writes drain slower.
// ---------------------------------------------------------------------------
__global__ __launch_bounds__(256, 8) void expand_kernel(
    const int* __restrict__ cat1, const int* __restrict__ cat2,
    const float* __restrict__ num1, const float* __restrict__ num2,
    const float* __restrict__ E1, const float* __restrict__ E2,
    const float* __restrict__ w1, const float* __restrict__ b1,
    const float* __restrict__ w2, const float* __restrict__ b2,
    const float* __restrict__ beta_ws, float* __restrict__ out)
{
    const int u  = blockIdx.x * 256 + threadIdx.x;  // [0, BT*16) = [0, 2^21)
    const int bt = u >> 4;
    const int c  = u & 15;

    const int   i1 = cat1[bt];
    const int   i2 = cat2[bt];
    const float x1 = num1[bt];
    const float x2 = num2[bt];

    const float4 e1  = ((const float4*)(E1 + (size_t)i1 * DD))[c];
    const float4 e2  = ((const float4*)(E2 + (size_t)i2 * DD))[c];
    const float4 wc1 = ((const float4*)w1)[c];
    const float4 bc1 = ((const float4*)b1)[c];
    const float4 wc2 = ((const float4*)w2)[c];
    const float4 bc2 = ((const float4*)b2)[c];
    const float4 n1  = make_float4(x1 * wc1.x + bc1.x, x1 * wc1.y + bc1.y,
                                   x1 * wc1.z + bc1.z, x1 * wc1.w + bc1.w);
    const float4 n2  = make_float4(x2 * wc2.x + bc2.x, x2 * wc2.y + bc2.y,
                                   x2 * wc2.z + bc2.z, x2 * wc2.w + bc2.w);

    const float4 bet = ((const float4*)beta_ws)[bt];   // (f0,f1,f2,f3)

    const float m1 = (i1 != -1 && i1 != 0) ? 1.f : 0.f;
    const float m2 = (i2 != -1 && i2 != 0) ? 1.f : 0.f;
    const float m3 = (x1 != -1.f && x1 != 0.f) ? 1.f : 0.f;
    const float m4 = (x2 != -1.f && x2 != 0.f) ? 1.f : 0.f;

    const int base = bt * 64 + c;                      // float4 index, f stride 16
    float4* outF = (float4*)(out + OFF_F);
    float4* outD = (float4*)(out + OFF_D);
    float4* outM = (float4*)(out + OFF_M);

    outF[base]      = e1;
    outF[base + 16] = e2;
    outF[base + 32] = n1;
    outF[base + 48] = n2;

    outD[base]      = make_float4(bet.x, bet.x, bet.x, bet.x);
    outD[base + 16] = make_float4(bet.y, bet.y, bet.y, bet.y);
    outD[base + 32] = make_float4(bet.z, bet.z, bet.z, bet.z);
    outD[base + 48] = make_float4(bet.w, bet.w, bet.w, bet.w);

    outM[base]      = make_float4(m1, m1, m1, m1);
    outM[base + 16] = make_float4(m2, m2, m2, m2);
    outM[base + 32] = make_float4(m3, m3, m3, m3);
    outM[base + 48] = make_float4(m4, m4, m4, m4);
}

extern "C" void kernel_launch(void* const* d_in, const int* in_sizes, int n_in,
                              void* d_out, int out_size, void* d_ws, size_t ws_size,
                              hipStream_t stream) {
    const int*   cat1  = (const int*)d_in[0];
    const int*   cat2  = (const int*)d_in[1];
    const float* num1  = (const float*)d_in[2];
    const float* num2  = (const float*)d_in[3];
    const float* times = (const float*)d_in[4];
    const float* E1    = (const float*)d_in[5];
    const float* E2    = (const float*)d_in[6];
    const float* w1    = (const float*)d_in[7];
    const float* b1    = (const float*)d_in[8];
    const float* w2    = (const float*)d_in[9];
    const float* b2    = (const float*)d_in[10];
    float* out     = (float*)d_out;
    float* beta_ws = (float*)d_ws;   // 4*B*T*4 = 2 MB scratch, [bt][f] layout

    beta_scan_kernel<<<4 * BB, 64, 0, stream>>>(cat1, cat2, num1, num2, times,
                                                beta_ws, out);

    expand_kernel<<<(BT * 16) / 256, 256, 0, stream>>>(
        cat1, cat2, num1, num2, E1, E2, w1, b1, w2, b2, beta_ws, out);
}